// Round 6
// baseline (984.918 us; speedup 1.0000x reference)
//
#include <hip/hip_runtime.h>
#include <math.h>

// Problem constants
#define DIMN   2048
#define NHEADS 16
#define HDIM   128
#define SEQ    2048
#define BATCH  2
#define SCALE  0.08838834764831845f  // 1/sqrt(128)
#define BHSD   (BATCH*NHEADS*SEQ*HDIM)  // 8388608

typedef unsigned short u16;
typedef __attribute__((ext_vector_type(8))) unsigned short ushort8v;
typedef __attribute__((ext_vector_type(8))) short bf16x8;   // MFMA A/B frag (8 bf16)
typedef __attribute__((ext_vector_type(4))) float f32x4;    // MFMA C/D frag

#define MFMA16(a,b,c) __builtin_amdgcn_mfma_f32_16x16x32_bf16(a,b,c,0,0,0)

__device__ inline float bf2f(u16 h) {
    union { unsigned u; float f; } v; v.u = ((unsigned)h) << 16; return v.f;
}
__device__ inline u16 f2bf(float f) {   // round-to-nearest-even bf16
    union { float f; unsigned u; } v; v.f = f;
    unsigned r = v.u + 0x7FFF + ((v.u >> 16) & 1);
    return (u16)(r >> 16);
}
__device__ inline ushort8v pack8(const float4& a, const float4& b) {
    ushort8v r;
    r[0]=f2bf(a.x); r[1]=f2bf(a.y); r[2]=f2bf(a.z); r[3]=f2bf(a.w);
    r[4]=f2bf(b.x); r[5]=f2bf(b.y); r[6]=f2bf(b.z); r[7]=f2bf(b.w);
    return r;
}

// ---------------------------------------------------------------------------
// RoPE tables, compact [SEQ][64]. numpy fp32 pipeline, correctly-rounded trig.
__global__ __launch_bounds__(64) void rope_table_kernel(float* __restrict__ cosT,
                                                        float* __restrict__ sinT) {
    int pos = blockIdx.x;
    int i   = threadIdx.x;
    double e    = (double)(2 * i) / 128.0;
    float  invf = (float)pow(10000.0, -e);
    float  freq = (float)pos * invf;
    double fr = (double)freq;
    cosT[pos*64 + i] = (float)cos(fr);
    sinT[pos*64 + i] = (float)sin(fr);
}

// ---------------------------------------------------------------------------
// MFMA bf16 GEMM: C[M,N] = A[M,K] * W[N,K]^T. 128x128 tile, BK=32.
// 4 waves, 64x64 (4x4 16x16 frags) each, mfma_f32_16x16x32_bf16.
// MODE 0: A fp32 (x). q,k scattered bf16 [B,H,S,D]; V scattered TRANSPOSED
//         [B,H,D,S] (packed ushort4 over 4 consecutive s) so attention can
//         read PV B-frags directly from global with zero overfetch.
// MODE 1: A bf16 (attn out), output fp32 row-major (d_out).
template<int MODE>
__global__ __launch_bounds__(256) void gemm_mfma(const void* __restrict__ Av,
                                                 const float* __restrict__ W,
                                                 void* __restrict__ o0,
                                                 void* __restrict__ o1,
                                                 void* __restrict__ o2,
                                                 int K) {
    __shared__ __align__(16) u16 Alds[128][40];   // [m][k], 80B rows
    __shared__ __align__(16) u16 Blds[128][40];   // [n][k]

    const int tid  = threadIdx.x;
    const int srow = tid >> 1;            // staging row 0..127
    const int skk  = (tid & 1) * 16;      // staging k-segment
    const int w    = tid >> 6;            // wave 0..3
    const int l    = tid & 63;
    const int lr   = l & 15;
    const int lk   = l >> 4;
    const int wr   = (w >> 1) * 64;       // wave row offset in tile
    const int wc   = (w & 1) * 64;        // wave col offset
    const int bx   = blockIdx.x;
    const int by   = blockIdx.y;

    const float* aF = (const float*)Av + (long)(by*128 + srow) * K;
    const u16*   aH = (const u16*)Av   + (long)(by*128 + srow) * K;
    const float* bF = W + (long)(bx*128 + srow) * K;

    f32x4 acc[4][4];
    #pragma unroll
    for (int i = 0; i < 4; ++i)
        #pragma unroll
        for (int j = 0; j < 4; ++j) acc[i][j] = f32x4{0.f,0.f,0.f,0.f};

    // Prologue: load k-tile 0 into regs
    float4 av[4]; ushort8v ah[2]; float4 bv[4];
    if constexpr (MODE == 0) {
        #pragma unroll
        for (int j = 0; j < 4; ++j) av[j] = *(const float4*)(aF + skk + 4*j);
    } else {
        #pragma unroll
        for (int j = 0; j < 2; ++j) ah[j] = *(const ushort8v*)(aH + skk + 8*j);
    }
    #pragma unroll
    for (int j = 0; j < 4; ++j) bv[j] = *(const float4*)(bF + skk + 4*j);

    for (int k0 = 0; k0 < K; k0 += 32) {
        __syncthreads();   // previous tile's frag reads done
        if constexpr (MODE == 0) {
            *(ushort8v*)&Alds[srow][skk]     = pack8(av[0], av[1]);
            *(ushort8v*)&Alds[srow][skk + 8] = pack8(av[2], av[3]);
        } else {
            *(ushort8v*)&Alds[srow][skk]     = ah[0];
            *(ushort8v*)&Alds[srow][skk + 8] = ah[1];
        }
        *(ushort8v*)&Blds[srow][skk]     = pack8(bv[0], bv[1]);
        *(ushort8v*)&Blds[srow][skk + 8] = pack8(bv[2], bv[3]);
        __syncthreads();   // tile staged

        // Prefetch next k-tile (global latency hides under MFMAs)
        if (k0 + 32 < K) {
            if constexpr (MODE == 0) {
                #pragma unroll
                for (int j = 0; j < 4; ++j) av[j] = *(const float4*)(aF + k0+32 + skk + 4*j);
            } else {
                #pragma unroll
                for (int j = 0; j < 2; ++j) ah[j] = *(const ushort8v*)(aH + k0+32 + skk + 8*j);
            }
            #pragma unroll
            for (int j = 0; j < 4; ++j) bv[j] = *(const float4*)(bF + k0+32 + skk + 4*j);
        }

        // Compute: 8 ds_read_b128 + 16 MFMA per wave
        bf16x8 af[4], bf[4];
        #pragma unroll
        for (int mr = 0; mr < 4; ++mr)
            af[mr] = *(const bf16x8*)&Alds[wr + mr*16 + lr][lk*8];
        #pragma unroll
        for (int nr = 0; nr < 4; ++nr)
            bf[nr] = *(const bf16x8*)&Blds[wc + nr*16 + lr][lk*8];
        #pragma unroll
        for (int mr = 0; mr < 4; ++mr)
            #pragma unroll
            for (int nr = 0; nr < 4; ++nr)
                acc[mr][nr] = MFMA16(af[mr], bf[nr], acc[mr][nr]);
    }

    // Epilogue. C row = wr+mr*16+lk*4+reg, col = wc+nr*16+lr.
    if constexpr (MODE == 0) {
        const int t = bx >> 4;      // 0=q 1=k 2=v
        const int h = bx & 15;
        if (t < 2) {
            u16* dst = (t == 0) ? (u16*)o0 : (u16*)o1;
            #pragma unroll
            for (int mr = 0; mr < 4; ++mr)
                #pragma unroll
                for (int r = 0; r < 4; ++r) {
                    int m = by*128 + wr + mr*16 + lk*4 + r;
                    int b = m >> 11, s = m & 2047;
                    long ro = ((long)(b*NHEADS + h) * SEQ + s) * HDIM;
                    #pragma unroll
                    for (int nr = 0; nr < 4; ++nr)
                        dst[ro + wc + nr*16 + lr] = f2bf(acc[mr][nr][r]);
                }
        } else {
            // V transposed: vt[b,h,d,s]; 4 consecutive s (=r) pack into ushort4
            u16* dst = (u16*)o2;
            #pragma unroll
            for (int mr = 0; mr < 4; ++mr) {
                int m0 = by*128 + wr + mr*16 + lk*4;   // r=0 row; all 4 r same batch
                int b0 = m0 >> 11, s0 = m0 & 2047;
                long hb = (long)(b0*NHEADS + h) * SEQ * HDIM;
                #pragma unroll
                for (int nr = 0; nr < 4; ++nr) {
                    long ad = hb + (long)(wc + nr*16 + lr) * SEQ + s0;
                    ushort4 vv;
                    vv.x = f2bf(acc[mr][nr][0]); vv.y = f2bf(acc[mr][nr][1]);
                    vv.z = f2bf(acc[mr][nr][2]); vv.w = f2bf(acc[mr][nr][3]);
                    *(ushort4*)&dst[ad] = vv;
                }
            }
        }
    } else {
        float* out = (float*)o0;
        #pragma unroll
        for (int mr = 0; mr < 4; ++mr)
            #pragma unroll
            for (int r = 0; r < 4; ++r) {
                long m = by*128 + wr + mr*16 + lk*4 + r;
                #pragma unroll
                for (int nr = 0; nr < 4; ++nr)
                    out[m*DIMN + bx*128 + wc + nr*16 + lr] = acc[mr][nr][r];
            }
    }
}

// ---------------------------------------------------------------------------
// In-place RoPE on bf16 q and k ([B,H,S,D]). Tables [SEQ][64] fp32.
__global__ __launch_bounds__(256) void rope_apply_kernel(u16* __restrict__ q,
                                                         u16* __restrict__ k,
                                                         const float* __restrict__ cosT,
                                                         const float* __restrict__ sinT) {
    int idx = blockIdx.x * 256 + threadIdx.x;
    int i  = idx & 63;
    int s  = (idx >> 6) & (SEQ - 1);
    int bh = idx >> 17;
    long base = ((long)bh * SEQ + s) * HDIM;
    float c  = cosT[s*64 + i];
    float sn = sinT[s*64 + i];
    float q1 = bf2f(q[base + i]), q2 = bf2f(q[base + 64 + i]);
    q[base + i]      = f2bf(q1 * c - q2 * sn);
    q[base + 64 + i] = f2bf(q2 * c + q1 * sn);
    float k1 = bf2f(k[base + i]), k2 = bf2f(k[base + 64 + i]);
    k[base + i]      = f2bf(k1 * c - k2 * sn);
    k[base + 64 + i] = f2bf(k2 * c + k1 * sn);
}

// ---------------------------------------------------------------------------
// Flash attention, MFMA, NO K/V LDS. QBLK=64 (16 q-rows/wave), KT=32.
// K B-frags and transposed-V B-frags load straight from global (L1/L2-resident:
// K-tile 8KB + V-tile 8KB shared by the block's 4 waves; frag slices exactly
// tile the rows -> zero overfetch). LDS holds only the 5KB P bounce.
// V-frag loads issue before softmax so their latency hides under it.
__global__ __launch_bounds__(256) void attn_mfma(const u16* __restrict__ qb,
                                                 const u16* __restrict__ kb,
                                                 const u16* __restrict__ vt,
                                                 u16* __restrict__ ao) {
    __shared__ __align__(16) u16 Pst[64][40];    // [q][key] bf16

    const int tid = threadIdx.x;
    const int w   = tid >> 6;
    const int l   = tid & 63;
    const int lr  = l & 15;
    const int lk  = l >> 4;
    const int bq  = (SEQ/64 - 1) - blockIdx.x;   // heavy blocks first
    const int h   = blockIdx.y;
    const int b   = blockIdx.z;
    const int q0  = bq * 64;

    const long headoff = ((long)(b*NHEADS + h)) * SEQ * HDIM;
    const u16* qh = qb + headoff;
    const u16* kh = kb + headoff;
    const u16* vh = vt + headoff;     // [D][S] within head

    // Q A-frags: wave w owns q-rows q0+w*16..+15 (row lr, k-slice lk*8).
    bf16x8 qf[4];
    {
        const u16* qrow = qh + (long)(q0 + w*16 + lr) * HDIM;
        #pragma unroll
        for (int ds = 0; ds < 4; ++ds)
            qf[ds] = *(const bf16x8*)(qrow + ds*32 + lk*8);
    }

    f32x4 accO[8];
    #pragma unroll
    for (int nb = 0; nb < 8; ++nb) accO[nb] = f32x4{0.f,0.f,0.f,0.f};
    float m_[4], l_[4];
    #pragma unroll
    for (int r = 0; r < 4; ++r) { m_[r] = -1e30f; l_[r] = 0.f; }

    const int ntiles = 2*bq + 2;
    for (int t = 0; t < ntiles; ++t) {
        const int kt0 = t * 32;

        // QK^T: S[16q x 32k] per wave; K B-frags direct from global.
        f32x4 sv[2];
        #pragma unroll
        for (int kbk = 0; kbk < 2; ++kbk) {
            sv[kbk] = f32x4{0.f,0.f,0.f,0.f};
            const u16* krow = kh + (long)(kt0 + kbk*16 + lr) * HDIM;
            #pragma unroll
            for (int ds = 0; ds < 4; ++ds) {
                bf16x8 kf = *(const bf16x8*)(krow + ds*32 + lk*8);
                sv[kbk] = MFMA16(qf[ds], kf, sv[kbk]);
            }
        }

        // V B-frags for THIS tile: issue now, consumed after softmax+barriers.
        bf16x8 vf[8];
        #pragma unroll
        for (int nb = 0; nb < 8; ++nb)
            vf[nb] = *(const bf16x8*)(vh + (long)(nb*16 + lr) * SEQ + kt0 + lk*8);

        // scale + causal mask (only last 2 tiles)
        const bool masked = (t >= 2*bq);
        #pragma unroll
        for (int kbk = 0; kbk < 2; ++kbk)
            #pragma unroll
            for (int r = 0; r < 4; ++r) {
                float v = sv[kbk][r] * SCALE;
                if (masked) {
                    int kg = kt0 + kbk*16 + lr;
                    int rg = q0 + w*16 + lk*4 + r;
                    if (kg > rg) v = -1e30f;
                }
                sv[kbk][r] = v;
            }

        // online softmax (rows across 16 lr lanes; reduce over lr)
        float p0[4], p1[4];
        #pragma unroll
        for (int r = 0; r < 4; ++r) {
            float mx = fmaxf(sv[0][r], sv[1][r]);
            #pragma unroll
            for (int o = 1; o < 16; o <<= 1) mx = fmaxf(mx, __shfl_xor(mx, o, 64));
            float mn = fmaxf(m_[r], mx);
            float ef = expf(m_[r] - mn);
            p0[r] = expf(sv[0][r] - mn);
            p1[r] = expf(sv[1][r] - mn);
            float rs = p0[r] + p1[r];
            #pragma unroll
            for (int o = 1; o < 16; o <<= 1) rs += __shfl_xor(rs, o, 64);
            l_[r] = l_[r] * ef + rs;
            m_[r] = mn;
            #pragma unroll
            for (int nb = 0; nb < 8; ++nb) accO[nb][r] *= ef;
        }

        __syncthreads();   // prev tile's pf reads done
        #pragma unroll
        for (int r = 0; r < 4; ++r) {
            int qrow = w*16 + lk*4 + r;
            Pst[qrow][lr]      = f2bf(p0[r]);
            Pst[qrow][16 + lr] = f2bf(p1[r]);
        }
        __syncthreads();   // P staged

        // PV: O[16q x 128d] += P[16x32] . V[32x128]
        bf16x8 pf = *(const bf16x8*)&Pst[w*16 + lr][lk*8];
        #pragma unroll
        for (int nb = 0; nb < 8; ++nb)
            accO[nb] = MFMA16(pf, vf[nb], accO[nb]);
    }

    // Write O (bf16) in [B,S,H*D]
    #pragma unroll
    for (int r = 0; r < 4; ++r) {
        float inv = 1.0f / l_[r];
        long ro = ((long)b * SEQ + q0 + w*16 + lk*4 + r) * DIMN + h * HDIM;
        #pragma unroll
        for (int nb = 0; nb < 8; ++nb)
            ao[ro + nb*16 + lr] = f2bf(accO[nb][r] * inv);
    }
}

// ---------------------------------------------------------------------------
// ws layout (65 MB): cosT/sinT [2048][64] fp32; qb,kb [B,H,S,D] bf16;
// vt [B,H,D,S] bf16 (transposed V); ao [B,S,H*D] bf16.
// (R2 lesson: 136 MB overflowed ws_size; keep <= 65 MB.)
extern "C" void kernel_launch(void* const* d_in, const int* in_sizes, int n_in,
                              void* d_out, int out_size, void* d_ws, size_t ws_size,
                              hipStream_t stream) {
    const float* x     = (const float*)d_in[0];
    const float* qkv_w = (const float*)d_in[1];
    const float* out_w = (const float*)d_in[2];
    float* out = (float*)d_out;
    float* ws  = (float*)d_ws;

    float* cosT = ws;
    float* sinT = ws + SEQ*64;
    u16* qb = (u16*)(ws + 2*SEQ*64);
    u16* kb = qb + BHSD;
    u16* vt = kb + BHSD;
    u16* ao = vt + BHSD;

    rope_table_kernel<<<dim3(SEQ), dim3(64), 0, stream>>>(cosT, sinT);

    // QKV projection (MFMA); q,k -> [B,H,S,D], v -> transposed [B,H,D,S]
    gemm_mfma<0><<<dim3(48, 32), dim3(256), 0, stream>>>(x, qkv_w, qb, kb, vt, DIMN);

    // RoPE in-place on q,k
    rope_apply_kernel<<<dim3((BATCH*NHEADS*SEQ*64)/256), dim3(256), 0, stream>>>(qb, kb, cosT, sinT);

    // Flash attention (MFMA, no K/V LDS)
    attn_mfma<<<dim3(SEQ/64, NHEADS, BATCH), dim3(256), 0, stream>>>(qb, kb, vt, ao);

    // Output projection (MFMA, bf16 A, fp32 out)
    gemm_mfma<1><<<dim3(16, 32), dim3(256), 0, stream>>>(ao, out_w, out, nullptr, nullptr, DIMN);
}